// Round 1
// baseline (493.158 us; speedup 1.0000x reference)
//
#include <hip/hip_runtime.h>
#include <stdint.h>

#define TTOK 1024
#define DMODEL 1024
#define NEXP 16
#define TOPK 4
#define INTER 512
#define NSHI 1024
#define RSCALE 2.5f

typedef __bf16 bf16;
typedef __bf16 bf16x8 __attribute__((ext_vector_type(8)));
typedef __bf16 bf16x4 __attribute__((ext_vector_type(4)));
typedef float f32x4 __attribute__((ext_vector_type(4)));

__device__ __forceinline__ void glds16(void* lds, const void* g) {
  __builtin_amdgcn_global_load_lds(
      (const __attribute__((address_space(1))) unsigned int*)g,
      (__attribute__((address_space(3))) unsigned int*)lds, 16, 0, 0);
}

// ---------------- routing: fp32 scores + group-limited top-k ----------------
__global__ __launch_bounds__(64)
void route_kernel(const float* __restrict__ x, const float* __restrict__ gw,
                  const float* __restrict__ gb, bf16* __restrict__ xbf,
                  int* __restrict__ tokIdx, float* __restrict__ tokW,
                  int* __restrict__ counts) {
  const int t = blockIdx.x;
  const int lane = threadIdx.x;
  float acc[NEXP];
#pragma unroll
  for (int e = 0; e < NEXP; ++e) acc[e] = 0.f;
#pragma unroll
  for (int i = 0; i < DMODEL / 64; ++i) {
    const int d = lane + i * 64;
    const float xv = x[t * DMODEL + d];
    xbf[t * DMODEL + d] = (bf16)xv;
#pragma unroll
    for (int e = 0; e < NEXP; ++e) acc[e] += xv * gw[e * DMODEL + d];
  }
#pragma unroll
  for (int e = 0; e < NEXP; ++e) {
#pragma unroll
    for (int off = 32; off > 0; off >>= 1) acc[e] += __shfl_xor(acc[e], off, 64);
  }
  if (lane == 0) {
    float sc[NEXP], s[NEXP];
#pragma unroll
    for (int e = 0; e < NEXP; ++e) {
      sc[e] = 1.f / (1.f + __expf(-acc[e]));
      s[e] = sc[e] + gb[e];
    }
    // group score = sum of top-2 of 4 = max pairwise sum
    float gsc[4];
#pragma unroll
    for (int g = 0; g < 4; ++g) {
      const float a = s[4 * g], b = s[4 * g + 1], c = s[4 * g + 2], d = s[4 * g + 3];
      gsc[g] = fmaxf(fmaxf(fmaxf(a + b, a + c), fmaxf(a + d, b + c)),
                     fmaxf(b + d, c + d));
    }
    // top-2 groups, ties -> lower index (strict > scans)
    int g0 = 0;
    for (int g = 1; g < 4; ++g) if (gsc[g] > gsc[g0]) g0 = g;
    int g1 = (g0 == 0) ? 1 : 0;
    for (int g = 0; g < 4; ++g) if (g != g0 && gsc[g] > gsc[g1]) g1 = g;

    float m[NEXP];
#pragma unroll
    for (int e = 0; e < NEXP; ++e) {
      const int g = e >> 2;
      m[e] = (g == g0 || g == g1) ? s[e] : -1.f;  // s=sigmoid+0 > 0 always
    }
    int idx[TOPK]; float wv[TOPK]; float wsum = 0.f;
    for (int k = 0; k < TOPK; ++k) {
      int am = 0; float best = m[0];
      for (int e2 = 1; e2 < NEXP; ++e2)
        if (m[e2] > best) { best = m[e2]; am = e2; }
      idx[k] = am; wv[k] = sc[am]; wsum += sc[am]; m[am] = -2.f;
    }
    const float scl = RSCALE / wsum;
    for (int k = 0; k < TOPK; ++k) {
      tokIdx[t * TOPK + k] = idx[k];
      tokW[t * TOPK + k] = wv[k] * scl;
      atomicAdd(&counts[idx[k]], 1);
    }
  }
}

__global__ void prefix_kernel(const int* __restrict__ counts, int* __restrict__ offs,
                              int* __restrict__ cursors, int* __restrict__ shOffs) {
  if (blockIdx.x == 0 && threadIdx.x == 0) {
    int acc = 0;
    for (int e = 0; e < NEXP; ++e) { offs[e] = acc; cursors[e] = acc; acc += counts[e]; }
    offs[NEXP] = acc;
    shOffs[0] = 0; shOffs[1] = TTOK;
  }
}

__global__ void fill_kernel(const int* __restrict__ tokIdx, const float* __restrict__ tokW,
                            int* __restrict__ cursors, int* __restrict__ slotTok,
                            float* __restrict__ slotW, int* __restrict__ shTok,
                            float* __restrict__ shW) {
  const int t = blockIdx.x * blockDim.x + threadIdx.x;
  if (t < TTOK) {
    shTok[t] = t; shW[t] = 1.f;
    for (int k = 0; k < TOPK; ++k) {
      const int e = tokIdx[t * TOPK + k];
      const int p = atomicAdd(&cursors[e], 1);
      slotTok[p] = t;
      slotW[p] = tokW[t * TOPK + k];
    }
  }
}

// ---------------- fp32 -> bf16 weight conversion (one pass) ----------------
struct CvtArgs {
  const float* src[6];
  bf16* dst[6];
  long n4[6];
};
__global__ void convert_kernel(CvtArgs a, long total4) {
  long i = (long)blockIdx.x * blockDim.x + threadIdx.x;
  const long stride = (long)gridDim.x * blockDim.x;
  for (; i < total4; i += stride) {
    long j = i; int s = 0;
    while (j >= a.n4[s]) { j -= a.n4[s]; ++s; }
    const float4 v = ((const float4*)a.src[s])[j];
    bf16x4 o;
    o.x = (bf16)v.x; o.y = (bf16)v.y; o.z = (bf16)v.z; o.w = (bf16)v.w;
    ((bf16x4*)a.dst[s])[j] = o;
  }
}

// ---------------- gate+up grouped GEMM with fused SwiGLU ----------------
// C_g = A*Wg^T, C_u = A*Wu^T (A rows gathered via slotTok); out = silu(C_g)*C_u
__global__ __launch_bounds__(256, 2)
void gateup_gemm(const bf16* __restrict__ xbf, const int* __restrict__ slotTok,
                 const int* __restrict__ offs, const bf16* __restrict__ Wg,
                 const bf16* __restrict__ Wu, long wstride, int Kd,
                 bf16* __restrict__ outI, int ldI) {
  const int e = blockIdx.z;
  const int rowStart = offs[e] + blockIdx.y * 128;
  const int rowEnd = offs[e + 1];
  if (rowStart >= rowEnd) return;
  const int n0 = blockIdx.x * 128;
  const bf16* wg = Wg + (long)e * wstride;
  const bf16* wu = Wu + (long)e * wstride;

  __shared__ __attribute__((aligned(16))) bf16 As[4][128][8];
  __shared__ __attribute__((aligned(16))) bf16 Bg[4][128][8];
  __shared__ __attribute__((aligned(16))) bf16 Bu[4][128][8];
  __shared__ int tokS[128];

  const int tid = threadIdx.x;
  const int lane = tid & 63;
  const int wv = tid >> 6;
  if (tid < 128) {
    const int r = rowStart + tid;
    tokS[tid] = slotTok[r < rowEnd ? r : rowStart];  // pad rows -> any valid token
  }
  __syncthreads();

  const int kc = wv;  // each wave stages one k-chunk of all three tiles
  const long t0 = tokS[lane];
  const long t1 = tokS[64 + lane];
  const bf16* a0 = xbf + t0 * DMODEL + kc * 8;
  const bf16* a1 = xbf + t1 * DMODEL + kc * 8;
  const bf16* g0p = wg + (long)(n0 + lane) * Kd + kc * 8;
  const bf16* g1p = g0p + (long)64 * Kd;
  const bf16* u0p = wu + (long)(n0 + lane) * Kd + kc * 8;
  const bf16* u1p = u0p + (long)64 * Kd;
  void* dA0 = (void*)&As[kc][0][0];
  void* dA1 = (void*)&As[kc][64][0];
  void* dG0 = (void*)&Bg[kc][0][0];
  void* dG1 = (void*)&Bg[kc][64][0];
  void* dU0 = (void*)&Bu[kc][0][0];
  void* dU1 = (void*)&Bu[kc][64][0];

  const int q = lane >> 4;
  const int l15 = lane & 15;
  const int wm = (wv >> 1) * 64;
  const int wn = (wv & 1) * 64;

  const f32x4 fz = {0.f, 0.f, 0.f, 0.f};
  f32x4 accG[4][4], accU[4][4];
#pragma unroll
  for (int i = 0; i < 4; ++i)
#pragma unroll
    for (int j = 0; j < 4; ++j) { accG[i][j] = fz; accU[i][j] = fz; }

  for (int k0 = 0; k0 < Kd; k0 += 32) {
    glds16(dA0, a0 + k0);
    glds16(dA1, a1 + k0);
    glds16(dG0, g0p + k0);
    glds16(dG1, g1p + k0);
    glds16(dU0, u0p + k0);
    glds16(dU1, u1p + k0);
    __syncthreads();
    bf16x8 aF[4], gF[4], uF[4];
#pragma unroll
    for (int mi = 0; mi < 4; ++mi)
      aF[mi] = *(const bf16x8*)&As[q][wm + mi * 16 + l15][0];
#pragma unroll
    for (int ni = 0; ni < 4; ++ni) {
      gF[ni] = *(const bf16x8*)&Bg[q][wn + ni * 16 + l15][0];
      uF[ni] = *(const bf16x8*)&Bu[q][wn + ni * 16 + l15][0];
    }
#pragma unroll
    for (int mi = 0; mi < 4; ++mi)
#pragma unroll
      for (int ni = 0; ni < 4; ++ni) {
        accG[mi][ni] = __builtin_amdgcn_mfma_f32_16x16x32_bf16(aF[mi], gF[ni], accG[mi][ni], 0, 0, 0);
        accU[mi][ni] = __builtin_amdgcn_mfma_f32_16x16x32_bf16(aF[mi], uF[ni], accU[mi][ni], 0, 0, 0);
      }
    __syncthreads();
  }
#pragma unroll
  for (int mi = 0; mi < 4; ++mi)
#pragma unroll
    for (int r = 0; r < 4; ++r) {
      const int rowLoc = wm + mi * 16 + q * 4 + r;  // D: row=quad*4+reg
      const int slotRow = rowStart + rowLoc;
      if (slotRow < rowEnd) {
#pragma unroll
        for (int ni = 0; ni < 4; ++ni) {
          const float gg = accG[mi][ni][r];
          const float uu = accU[mi][ni][r];
          const float sv = gg / (1.f + __expf(-gg)) * uu;
          outI[(long)slotRow * ldI + (n0 + wn + ni * 16 + l15)] = (bf16)sv;
        }
      }
    }
}

// ---------------- down grouped GEMM with fused weighted scatter ----------------
__global__ __launch_bounds__(256, 2)
void down_gemm(const bf16* __restrict__ A, const int* __restrict__ slotTok,
               const float* __restrict__ slotW, const int* __restrict__ offs,
               const bf16* __restrict__ Wd, long wstride, int Kd,
               float* __restrict__ out, int accumulate) {
  const int e = blockIdx.z;
  const int rowStart = offs[e] + blockIdx.y * 128;
  const int rowEnd = offs[e + 1];
  if (rowStart >= rowEnd) return;
  const int n0 = blockIdx.x * 128;
  const bf16* wd = Wd + (long)e * wstride;

  __shared__ __attribute__((aligned(16))) bf16 As[4][128][8];
  __shared__ __attribute__((aligned(16))) bf16 Bs[4][128][8];
  __shared__ int tokS[128];
  __shared__ float wS[128];

  const int tid = threadIdx.x;
  const int lane = tid & 63;
  const int wv = tid >> 6;
  if (tid < 128) {
    const int r = rowStart + tid;
    const bool valid = r < rowEnd;
    tokS[tid] = valid ? slotTok[r] : 0;
    wS[tid] = valid ? slotW[r] : 0.f;
  }
  __syncthreads();

  const int kc = wv;
  const bf16* a0 = A + (long)(rowStart + lane) * Kd + kc * 8;  // rows = slots directly
  const bf16* a1 = a0 + (long)64 * Kd;
  const bf16* b0 = wd + (long)(n0 + lane) * Kd + kc * 8;
  const bf16* b1 = b0 + (long)64 * Kd;
  void* dA0 = (void*)&As[kc][0][0];
  void* dA1 = (void*)&As[kc][64][0];
  void* dB0 = (void*)&Bs[kc][0][0];
  void* dB1 = (void*)&Bs[kc][64][0];

  const int q = lane >> 4;
  const int l15 = lane & 15;
  const int wm = (wv >> 1) * 64;
  const int wn = (wv & 1) * 64;

  const f32x4 fz = {0.f, 0.f, 0.f, 0.f};
  f32x4 acc[4][4];
#pragma unroll
  for (int i = 0; i < 4; ++i)
#pragma unroll
    for (int j = 0; j < 4; ++j) acc[i][j] = fz;

  for (int k0 = 0; k0 < Kd; k0 += 32) {
    glds16(dA0, a0 + k0);
    glds16(dA1, a1 + k0);
    glds16(dB0, b0 + k0);
    glds16(dB1, b1 + k0);
    __syncthreads();
    bf16x8 aF[4], bF[4];
#pragma unroll
    for (int mi = 0; mi < 4; ++mi)
      aF[mi] = *(const bf16x8*)&As[q][wm + mi * 16 + l15][0];
#pragma unroll
    for (int ni = 0; ni < 4; ++ni)
      bF[ni] = *(const bf16x8*)&Bs[q][wn + ni * 16 + l15][0];
#pragma unroll
    for (int mi = 0; mi < 4; ++mi)
#pragma unroll
      for (int ni = 0; ni < 4; ++ni)
        acc[mi][ni] = __builtin_amdgcn_mfma_f32_16x16x32_bf16(aF[mi], bF[ni], acc[mi][ni], 0, 0, 0);
    __syncthreads();
  }
#pragma unroll
  for (int mi = 0; mi < 4; ++mi)
#pragma unroll
    for (int r = 0; r < 4; ++r) {
      const int rowLoc = wm + mi * 16 + q * 4 + r;
      const int slotRow = rowStart + rowLoc;
      if (slotRow < rowEnd) {
        const long tok = tokS[rowLoc];
        const float wgt = wS[rowLoc];
#pragma unroll
        for (int ni = 0; ni < 4; ++ni) {
          const int col = n0 + wn + ni * 16 + l15;
          const float val = acc[mi][ni][r];
          if (accumulate) atomicAdd(&out[tok * DMODEL + col], wgt * val);
          else out[tok * DMODEL + col] = val;
        }
      }
    }
}

extern "C" void kernel_launch(void* const* d_in, const int* in_sizes, int n_in,
                              void* d_out, int out_size, void* d_ws, size_t ws_size,
                              hipStream_t stream) {
  const float* x  = (const float*)d_in[0];
  // d_in[1] = token_mask (all ones; unused by the reference computation)
  const float* gw = (const float*)d_in[2];
  const float* gb = (const float*)d_in[3];
  const float* gp = (const float*)d_in[4];
  const float* up = (const float*)d_in[5];
  const float* dp = (const float*)d_in[6];
  const float* sg = (const float*)d_in[7];
  const float* su = (const float*)d_in[8];
  const float* sd = (const float*)d_in[9];
  float* out = (float*)d_out;

  char* base = (char*)d_ws;
  size_t off = 0;
  auto alloc = [&](size_t bytes) -> char* {
    off = (off + 255) & ~(size_t)255;
    char* p = base + off;
    off += bytes;
    return p;
  };
  bf16* wgp = (bf16*)alloc((size_t)NEXP * INTER * DMODEL * 2);
  bf16* wup = (bf16*)alloc((size_t)NEXP * INTER * DMODEL * 2);
  bf16* wdp = (bf16*)alloc((size_t)NEXP * DMODEL * INTER * 2);
  bf16* wsg = (bf16*)alloc((size_t)NSHI * DMODEL * 2);
  bf16* wsu = (bf16*)alloc((size_t)NSHI * DMODEL * 2);
  bf16* wsd = (bf16*)alloc((size_t)DMODEL * NSHI * 2);
  bf16* xbf = (bf16*)alloc((size_t)TTOK * DMODEL * 2);
  bf16* interRt = (bf16*)alloc((size_t)(TTOK * TOPK + 128) * INTER * 2);  // +128 row pad
  bf16* interSh = (bf16*)alloc((size_t)TTOK * NSHI * 2);
  int* tokIdx = (int*)alloc(TTOK * TOPK * 4);
  float* tokW = (float*)alloc(TTOK * TOPK * 4);
  int* slotTok = (int*)alloc(TTOK * TOPK * 4);
  float* slotW = (float*)alloc(TTOK * TOPK * 4);
  int* shTok = (int*)alloc(TTOK * 4);
  float* shW = (float*)alloc(TTOK * 4);
  int* counts = (int*)alloc(NEXP * 4);
  int* offs = (int*)alloc((NEXP + 1) * 4);
  int* cursors = (int*)alloc(NEXP * 4);
  int* shOffs = (int*)alloc(2 * 4);

  hipMemsetAsync(counts, 0, NEXP * 4, stream);

  route_kernel<<<TTOK, 64, 0, stream>>>(x, gw, gb, xbf, tokIdx, tokW, counts);
  prefix_kernel<<<1, 64, 0, stream>>>(counts, offs, cursors, shOffs);
  fill_kernel<<<(TTOK + 255) / 256, 256, 0, stream>>>(tokIdx, tokW, cursors,
                                                      slotTok, slotW, shTok, shW);

  CvtArgs ca;
  ca.src[0] = gp; ca.dst[0] = wgp; ca.n4[0] = (long)NEXP * INTER * DMODEL / 4;
  ca.src[1] = up; ca.dst[1] = wup; ca.n4[1] = (long)NEXP * INTER * DMODEL / 4;
  ca.src[2] = dp; ca.dst[2] = wdp; ca.n4[2] = (long)NEXP * DMODEL * INTER / 4;
  ca.src[3] = sg; ca.dst[3] = wsg; ca.n4[3] = (long)NSHI * DMODEL / 4;
  ca.src[4] = su; ca.dst[4] = wsu; ca.n4[4] = (long)NSHI * DMODEL / 4;
  ca.src[5] = sd; ca.dst[5] = wsd; ca.n4[5] = (long)DMODEL * NSHI / 4;
  const long total4 = ca.n4[0] * 3 + ca.n4[3] * 3;
  convert_kernel<<<4096, 256, 0, stream>>>(ca, total4);

  // shared expert (identity slot list), plain-store down fully initializes out
  gateup_gemm<<<dim3(NSHI / 128, TTOK / 128, 1), 256, 0, stream>>>(
      xbf, shTok, shOffs, wsg, wsu, 0, DMODEL, interSh, NSHI);
  down_gemm<<<dim3(DMODEL / 128, TTOK / 128, 1), 256, 0, stream>>>(
      interSh, shTok, shW, shOffs, wsd, 0, NSHI, out, 0);

  // routed experts (grouped, compact slot lists), weighted atomic scatter
  gateup_gemm<<<dim3(INTER / 128, TTOK / 128, NEXP), 256, 0, stream>>>(
      xbf, slotTok, offs, wgp, wup, (long)INTER * DMODEL, DMODEL, interRt, INTER);
  down_gemm<<<dim3(DMODEL / 128, TTOK / 128, NEXP), 256, 0, stream>>>(
      interRt, slotTok, slotW, offs, wdp, (long)DMODEL * INTER, INTER, out, 1);
}

// Round 2
// 313.379 us; speedup vs baseline: 1.5737x; 1.5737x over previous
//
#include <hip/hip_runtime.h>
#include <stdint.h>

#define TTOK 1024
#define DMODEL 1024
#define NEXP 16
#define TOPK 4
#define INTER 512
#define NSHI 1024
#define RSCALE 2.5f

typedef __bf16 bf16;
typedef __bf16 bf16x8 __attribute__((ext_vector_type(8)));
typedef __bf16 bf16x4 __attribute__((ext_vector_type(4)));
typedef float f32x4 __attribute__((ext_vector_type(4)));

__device__ __forceinline__ void glds16(void* lds, const void* g) {
  __builtin_amdgcn_global_load_lds(
      (const __attribute__((address_space(1))) unsigned int*)g,
      (__attribute__((address_space(3))) unsigned int*)lds, 16, 0, 0);
}

// ---------------- scores: logits = x @ gw^T, fp32 exact ----------------
// 256 blocks x 256 threads; 4 tokens/block; gw staged in LDS (swizzled +4e).
__global__ __launch_bounds__(256)
void scores_kernel(const float* __restrict__ x, const float* __restrict__ gw,
                   float* __restrict__ scores) {
  __shared__ float gws[16 * 1024];  // [e][(d + 4e) & 1023], 64 KB
  const int tid = threadIdx.x;
  const float4* gw4 = (const float4*)gw;
#pragma unroll
  for (int i0 = 0; i0 < 4096; i0 += 256) {
    const int i = i0 + tid;
    const int e = i >> 8;
    const int dq = (i & 255) << 2;
    const int dd = (dq + 4 * e) & 1023;
    ((float4*)gws)[(e << 8) + (dd >> 2)] = gw4[i];
  }
  __syncthreads();
  const int kq = tid >> 6;      // k-quarter 0..3
  const int lane = tid & 63;
  const int tl = lane >> 4;     // token-local 0..3
  const int e = lane & 15;      // expert 0..15
  const long token = (long)blockIdx.x * 4 + tl;
  float acc = 0.f;
  const int dbase = kq * 256;
#pragma unroll 8
  for (int i = 0; i < 256; i += 4) {
    const int d = dbase + i;
    const float4 xv = *(const float4*)&x[token * DMODEL + d];
    const float4 wv = *(const float4*)&gws[(e << 10) + ((d + 4 * e) & 1023)];
    acc += xv.x * wv.x + xv.y * wv.y + xv.z * wv.z + xv.w * wv.w;
  }
  __syncthreads();
  gws[kq * 64 + lane] = acc;    // reuse LDS as reduce scratch
  __syncthreads();
  if (kq == 0) {
    const float s = gws[lane] + gws[64 + lane] + gws[128 + lane] + gws[192 + lane];
    scores[token * 16 + e] = s;  // pre-sigmoid logits
  }
}

// ---------------- top-k: one thread per token ----------------
__global__ __launch_bounds__(256)
void topk_kernel(const float* __restrict__ scores, const float* __restrict__ gb,
                 int* __restrict__ tokIdx, float* __restrict__ tokW,
                 int* __restrict__ counts) {
  __shared__ int h[NEXP];
  const int tid = threadIdx.x;
  if (tid < NEXP) h[tid] = 0;
  __syncthreads();
  const int t = blockIdx.x * 256 + tid;
  float sc[NEXP], s[NEXP];
#pragma unroll
  for (int e = 0; e < NEXP; ++e) {
    const float l = scores[t * NEXP + e];
    sc[e] = 1.f / (1.f + expf(-l));
    s[e] = sc[e] + gb[e];
  }
  float gsc[4];
#pragma unroll
  for (int g = 0; g < 4; ++g) {
    const float a = s[4 * g], b = s[4 * g + 1], c = s[4 * g + 2], d = s[4 * g + 3];
    gsc[g] = fmaxf(fmaxf(fmaxf(a + b, a + c), fmaxf(a + d, b + c)),
                   fmaxf(b + d, c + d));
  }
  int g0 = 0;
  for (int g = 1; g < 4; ++g) if (gsc[g] > gsc[g0]) g0 = g;
  int g1 = (g0 == 0) ? 1 : 0;
  for (int g = 0; g < 4; ++g) if (g != g0 && gsc[g] > gsc[g1]) g1 = g;
  float m[NEXP];
#pragma unroll
  for (int e = 0; e < NEXP; ++e) {
    const int g = e >> 2;
    m[e] = (g == g0 || g == g1) ? s[e] : -1.f;  // selected s > 0 always
  }
  int idx[TOPK]; float wv[TOPK]; float wsum = 0.f;
  for (int k = 0; k < TOPK; ++k) {
    int am = 0; float best = m[0];
    for (int e2 = 1; e2 < NEXP; ++e2)
      if (m[e2] > best) { best = m[e2]; am = e2; }
    idx[k] = am; wv[k] = sc[am]; wsum += sc[am]; m[am] = -2.f;
  }
  const float scl = RSCALE / wsum;
  for (int k = 0; k < TOPK; ++k) {
    tokIdx[t * TOPK + k] = idx[k];
    tokW[t * TOPK + k] = wv[k] * scl;
    atomicAdd(&h[idx[k]], 1);   // LDS atomic
  }
  __syncthreads();
  if (tid < NEXP) atomicAdd(&counts[tid], h[tid]);  // 16 global atomics/block
}

__global__ void prefix_kernel(const int* __restrict__ counts, int* __restrict__ offs,
                              int* __restrict__ cursors) {
  if (threadIdx.x == 0) {
    int acc = 0;
    for (int e = 0; e < NEXP; ++e) { offs[e] = acc; cursors[e] = acc; acc += counts[e]; }
    offs[NEXP] = acc;
  }
}

// ---------------- fill: LDS-aggregated slot assignment ----------------
__global__ __launch_bounds__(256)
void fill_kernel(const int* __restrict__ tokIdx, const float* __restrict__ tokW,
                 int* __restrict__ cursors, int* __restrict__ slotTok,
                 float* __restrict__ slotW) {
  __shared__ int h[NEXP], base[NEXP];
  const int tid = threadIdx.x;
  if (tid < NEXP) h[tid] = 0;
  __syncthreads();
  const int t = blockIdx.x * 256 + tid;
  int myE[TOPK], myR[TOPK];
#pragma unroll
  for (int k = 0; k < TOPK; ++k) {
    myE[k] = tokIdx[t * TOPK + k];
    myR[k] = atomicAdd(&h[myE[k]], 1);  // LDS rank
  }
  __syncthreads();
  if (tid < NEXP) base[tid] = atomicAdd(&cursors[tid], h[tid]);
  __syncthreads();
#pragma unroll
  for (int k = 0; k < TOPK; ++k) {
    const int slot = base[myE[k]] + myR[k];
    slotTok[slot] = t;
    slotW[slot] = tokW[t * TOPK + k];
  }
}

// ---------------- fp32 -> bf16 conversion (weights + x), one pass ----------------
struct CvtArgs {
  const float* src[7];
  bf16* dst[7];
  long n4[7];
};
__global__ void convert_kernel(CvtArgs a, long total4) {
  long i = (long)blockIdx.x * blockDim.x + threadIdx.x;
  const long stride = (long)gridDim.x * blockDim.x;
  for (; i < total4; i += stride) {
    long j = i; int s = 0;
    while (j >= a.n4[s]) { j -= a.n4[s]; ++s; }
    const float4 v = ((const float4*)a.src[s])[j];
    bf16x4 o;
    o.x = (bf16)v.x; o.y = (bf16)v.y; o.z = (bf16)v.z; o.w = (bf16)v.w;
    ((bf16x4*)a.dst[s])[j] = o;
  }
}

// ---------------- merged gate+up grouped GEMM, fused SwiGLU ----------------
// z = 0..15: routed expert z (rows = compact slots); z = 16: shared expert
// (rows = tokens, identity). K = DMODEL = 1024 for all.
__global__ __launch_bounds__(256, 2)
void gateup_gemm(const bf16* __restrict__ xbf, const int* __restrict__ slotTok,
                 const int* __restrict__ offs, const bf16* __restrict__ Wg,
                 const bf16* __restrict__ Wu, const bf16* __restrict__ Sg,
                 const bf16* __restrict__ Su, bf16* __restrict__ outR,
                 bf16* __restrict__ outS) {
  const int z = blockIdx.z;
  const bool shd = (z == NEXP);
  const int nTiles = shd ? NSHI / 128 : INTER / 128;
  if ((int)blockIdx.x >= nTiles) return;
  const int rowStart = (shd ? 0 : offs[z]) + blockIdx.y * 128;
  const int rowEnd = shd ? TTOK : offs[z + 1];
  if (rowStart >= rowEnd) return;
  const int n0 = blockIdx.x * 128;
  const bf16* wg = shd ? Sg : Wg + (long)z * (INTER * DMODEL);
  const bf16* wu = shd ? Su : Wu + (long)z * (INTER * DMODEL);
  bf16* outI = shd ? outS : outR;
  const int ldI = shd ? NSHI : INTER;

  __shared__ __attribute__((aligned(16))) bf16 As[4][128][8];
  __shared__ __attribute__((aligned(16))) bf16 Bg[4][128][8];
  __shared__ __attribute__((aligned(16))) bf16 Bu[4][128][8];
  __shared__ int tokS[128];

  const int tid = threadIdx.x;
  const int lane = tid & 63;
  const int wv = tid >> 6;
  if (tid < 128) {
    const int r = rowStart + tid;
    tokS[tid] = shd ? (r < rowEnd ? r : rowStart)
                    : slotTok[r < rowEnd ? r : rowStart];
  }
  __syncthreads();

  const int kc = wv;  // each wave stages one k-chunk of all three tiles
  const long t0 = tokS[lane];
  const long t1 = tokS[64 + lane];
  const bf16* a0 = xbf + t0 * DMODEL + kc * 8;
  const bf16* a1 = xbf + t1 * DMODEL + kc * 8;
  const bf16* g0p = wg + (long)(n0 + lane) * DMODEL + kc * 8;
  const bf16* g1p = g0p + (long)64 * DMODEL;
  const bf16* u0p = wu + (long)(n0 + lane) * DMODEL + kc * 8;
  const bf16* u1p = u0p + (long)64 * DMODEL;
  void* dA0 = (void*)&As[kc][0][0];
  void* dA1 = (void*)&As[kc][64][0];
  void* dG0 = (void*)&Bg[kc][0][0];
  void* dG1 = (void*)&Bg[kc][64][0];
  void* dU0 = (void*)&Bu[kc][0][0];
  void* dU1 = (void*)&Bu[kc][64][0];

  const int q = lane >> 4;
  const int l15 = lane & 15;
  const int wm = (wv >> 1) * 64;
  const int wn = (wv & 1) * 64;

  const f32x4 fz = {0.f, 0.f, 0.f, 0.f};
  f32x4 accG[4][4], accU[4][4];
#pragma unroll
  for (int i = 0; i < 4; ++i)
#pragma unroll
    for (int j = 0; j < 4; ++j) { accG[i][j] = fz; accU[i][j] = fz; }

  for (int k0 = 0; k0 < DMODEL; k0 += 32) {
    glds16(dA0, a0 + k0);
    glds16(dA1, a1 + k0);
    glds16(dG0, g0p + k0);
    glds16(dG1, g1p + k0);
    glds16(dU0, u0p + k0);
    glds16(dU1, u1p + k0);
    __syncthreads();
    bf16x8 aF[4], gF[4], uF[4];
#pragma unroll
    for (int mi = 0; mi < 4; ++mi)
      aF[mi] = *(const bf16x8*)&As[q][wm + mi * 16 + l15][0];
#pragma unroll
    for (int ni = 0; ni < 4; ++ni) {
      gF[ni] = *(const bf16x8*)&Bg[q][wn + ni * 16 + l15][0];
      uF[ni] = *(const bf16x8*)&Bu[q][wn + ni * 16 + l15][0];
    }
#pragma unroll
    for (int mi = 0; mi < 4; ++mi)
#pragma unroll
      for (int ni = 0; ni < 4; ++ni) {
        accG[mi][ni] = __builtin_amdgcn_mfma_f32_16x16x32_bf16(aF[mi], gF[ni], accG[mi][ni], 0, 0, 0);
        accU[mi][ni] = __builtin_amdgcn_mfma_f32_16x16x32_bf16(aF[mi], uF[ni], accU[mi][ni], 0, 0, 0);
      }
    __syncthreads();
  }
#pragma unroll
  for (int mi = 0; mi < 4; ++mi)
#pragma unroll
    for (int r = 0; r < 4; ++r) {
      const int rowLoc = wm + mi * 16 + q * 4 + r;  // D: row=quad*4+reg
      const int slotRow = rowStart + rowLoc;
      if (slotRow < rowEnd) {
#pragma unroll
        for (int ni = 0; ni < 4; ++ni) {
          const float gg = accG[mi][ni][r];
          const float uu = accU[mi][ni][r];
          const float sv = gg / (1.f + __expf(-gg)) * uu;
          outI[(long)slotRow * ldI + (n0 + wn + ni * 16 + l15)] = (bf16)sv;
        }
      }
    }
}

// ---------------- merged down grouped GEMM, weighted atomic scatter ----------------
// out must be pre-zeroed. z = 0..15: routed (K=INTER); z = 16: shared (K=NSHI).
__global__ __launch_bounds__(256, 2)
void down_gemm(const bf16* __restrict__ AR, const bf16* __restrict__ AS,
               const int* __restrict__ slotTok, const float* __restrict__ slotW,
               const int* __restrict__ offs, const bf16* __restrict__ Wd,
               const bf16* __restrict__ Sd, float* __restrict__ out) {
  const int z = blockIdx.z;
  const bool shd = (z == NEXP);
  const int rowStart = (shd ? 0 : offs[z]) + blockIdx.y * 128;
  const int rowEnd = shd ? TTOK : offs[z + 1];
  if (rowStart >= rowEnd) return;
  const int n0 = blockIdx.x * 128;
  const int Kd = shd ? NSHI : INTER;
  const bf16* A = shd ? AS : AR;
  const bf16* wd = shd ? Sd : Wd + (long)z * (DMODEL * INTER);

  __shared__ __attribute__((aligned(16))) bf16 As[4][128][8];
  __shared__ __attribute__((aligned(16))) bf16 Bs[4][128][8];
  __shared__ int tokS[128];
  __shared__ float wS[128];

  const int tid = threadIdx.x;
  const int lane = tid & 63;
  const int wv = tid >> 6;
  if (tid < 128) {
    const int r = rowStart + tid;
    const bool valid = r < rowEnd;
    tokS[tid] = shd ? r : (valid ? slotTok[r] : 0);
    wS[tid] = shd ? 1.f : (valid ? slotW[r] : 0.f);
  }
  __syncthreads();

  const int kc = wv;
  const bf16* a0 = A + (long)(rowStart + lane) * Kd + kc * 8;
  const bf16* a1 = a0 + (long)64 * Kd;
  const bf16* b0 = wd + (long)(n0 + lane) * Kd + kc * 8;
  const bf16* b1 = b0 + (long)64 * Kd;
  void* dA0 = (void*)&As[kc][0][0];
  void* dA1 = (void*)&As[kc][64][0];
  void* dB0 = (void*)&Bs[kc][0][0];
  void* dB1 = (void*)&Bs[kc][64][0];

  const int q = lane >> 4;
  const int l15 = lane & 15;
  const int wm = (wv >> 1) * 64;
  const int wn = (wv & 1) * 64;

  const f32x4 fz = {0.f, 0.f, 0.f, 0.f};
  f32x4 acc[4][4];
#pragma unroll
  for (int i = 0; i < 4; ++i)
#pragma unroll
    for (int j = 0; j < 4; ++j) acc[i][j] = fz;

  for (int k0 = 0; k0 < Kd; k0 += 32) {
    glds16(dA0, a0 + k0);
    glds16(dA1, a1 + k0);
    glds16(dB0, b0 + k0);
    glds16(dB1, b1 + k0);
    __syncthreads();
    bf16x8 aF[4], bF[4];
#pragma unroll
    for (int mi = 0; mi < 4; ++mi)
      aF[mi] = *(const bf16x8*)&As[q][wm + mi * 16 + l15][0];
#pragma unroll
    for (int ni = 0; ni < 4; ++ni)
      bF[ni] = *(const bf16x8*)&Bs[q][wn + ni * 16 + l15][0];
#pragma unroll
    for (int mi = 0; mi < 4; ++mi)
#pragma unroll
      for (int ni = 0; ni < 4; ++ni)
        acc[mi][ni] = __builtin_amdgcn_mfma_f32_16x16x32_bf16(aF[mi], bF[ni], acc[mi][ni], 0, 0, 0);
    __syncthreads();
  }
#pragma unroll
  for (int mi = 0; mi < 4; ++mi)
#pragma unroll
    for (int r = 0; r < 4; ++r) {
      const int rowLoc = wm + mi * 16 + q * 4 + r;
      const int slotRow = rowStart + rowLoc;
      if (slotRow < rowEnd) {
        const long tok = tokS[rowLoc];
        const float wgt = wS[rowLoc];
#pragma unroll
        for (int ni = 0; ni < 4; ++ni) {
          const int col = n0 + wn + ni * 16 + l15;
          atomicAdd(&out[tok * DMODEL + col], wgt * acc[mi][ni][r]);
        }
      }
    }
}

extern "C" void kernel_launch(void* const* d_in, const int* in_sizes, int n_in,
                              void* d_out, int out_size, void* d_ws, size_t ws_size,
                              hipStream_t stream) {
  const float* x  = (const float*)d_in[0];
  const float* gw = (const float*)d_in[2];
  const float* gb = (const float*)d_in[3];
  const float* gp = (const float*)d_in[4];
  const float* up = (const float*)d_in[5];
  const float* dp = (const float*)d_in[6];
  const float* sg = (const float*)d_in[7];
  const float* su = (const float*)d_in[8];
  const float* sd = (const float*)d_in[9];
  float* out = (float*)d_out;

  char* base = (char*)d_ws;
  size_t off = 0;
  auto alloc = [&](size_t bytes) -> char* {
    off = (off + 255) & ~(size_t)255;
    char* p = base + off;
    off += bytes;
    return p;
  };
  bf16* wgp = (bf16*)alloc((size_t)NEXP * INTER * DMODEL * 2);
  bf16* wup = (bf16*)alloc((size_t)NEXP * INTER * DMODEL * 2);
  bf16* wdp = (bf16*)alloc((size_t)NEXP * DMODEL * INTER * 2);
  bf16* wsg = (bf16*)alloc((size_t)NSHI * DMODEL * 2);
  bf16* wsu = (bf16*)alloc((size_t)NSHI * DMODEL * 2);
  bf16* wsd = (bf16*)alloc((size_t)DMODEL * NSHI * 2);
  bf16* xbf = (bf16*)alloc((size_t)TTOK * DMODEL * 2);
  bf16* interRt = (bf16*)alloc((size_t)(TTOK * TOPK + 128) * INTER * 2);
  bf16* interSh = (bf16*)alloc((size_t)TTOK * NSHI * 2);
  float* scores = (float*)alloc((size_t)TTOK * NEXP * 4);
  int* tokIdx = (int*)alloc(TTOK * TOPK * 4);
  float* tokW = (float*)alloc(TTOK * TOPK * 4);
  int* slotTok = (int*)alloc(TTOK * TOPK * 4);
  float* slotW = (float*)alloc(TTOK * TOPK * 4);
  int* counts = (int*)alloc(NEXP * 4);
  int* offs = (int*)alloc((NEXP + 1) * 4);
  int* cursors = (int*)alloc(NEXP * 4);

  hipMemsetAsync(counts, 0, NEXP * 4, stream);
  hipMemsetAsync(out, 0, (size_t)TTOK * DMODEL * 4, stream);

  scores_kernel<<<TTOK / 4, 256, 0, stream>>>(x, gw, scores);
  topk_kernel<<<TTOK / 256, 256, 0, stream>>>(scores, gb, tokIdx, tokW, counts);
  prefix_kernel<<<1, 64, 0, stream>>>(counts, offs, cursors);
  fill_kernel<<<TTOK / 256, 256, 0, stream>>>(tokIdx, tokW, cursors, slotTok, slotW);

  CvtArgs ca;
  ca.src[0] = gp; ca.dst[0] = wgp; ca.n4[0] = (long)NEXP * INTER * DMODEL / 4;
  ca.src[1] = up; ca.dst[1] = wup; ca.n4[1] = (long)NEXP * INTER * DMODEL / 4;
  ca.src[2] = dp; ca.dst[2] = wdp; ca.n4[2] = (long)NEXP * DMODEL * INTER / 4;
  ca.src[3] = sg; ca.dst[3] = wsg; ca.n4[3] = (long)NSHI * DMODEL / 4;
  ca.src[4] = su; ca.dst[4] = wsu; ca.n4[4] = (long)NSHI * DMODEL / 4;
  ca.src[5] = sd; ca.dst[5] = wsd; ca.n4[5] = (long)DMODEL * NSHI / 4;
  ca.src[6] = x;  ca.dst[6] = xbf; ca.n4[6] = (long)TTOK * DMODEL / 4;
  long total4 = 0;
  for (int s = 0; s < 7; ++s) total4 += ca.n4[s];
  convert_kernel<<<4096, 256, 0, stream>>>(ca, total4);

  // merged gate+up (routed z=0..15, shared z=16)
  gateup_gemm<<<dim3(NSHI / 128, TTOK / 128, NEXP + 1), 256, 0, stream>>>(
      xbf, slotTok, offs, wgp, wup, wsg, wsu, interRt, interSh);
  // merged down, atomic accumulate into zeroed out
  down_gemm<<<dim3(DMODEL / 128, TTOK / 128, NEXP + 1), 256, 0, stream>>>(
      interRt, interSh, slotTok, slotW, offs, wdp, wsd, out);
}